// Round 3
// baseline (755.049 us; speedup 1.0000x reference)
//
#include <hip/hip_runtime.h>
#include <hip/hip_fp16.h>

// Problem constants (from reference): OUT=4096, IN=4096, G=16, TOK=8192
#define M_TOK 8192
#define N_OUT 4096
#define K_IN  4096
#define GRP   16

typedef __bf16 bf16x8 __attribute__((ext_vector_type(8)));
typedef float  f32x4  __attribute__((ext_vector_type(4)));
typedef unsigned short ushort8 __attribute__((ext_vector_type(8)));

__device__ __forceinline__ float bfbits(unsigned short h) {
    unsigned int u = ((unsigned int)h) << 16;
    return __builtin_bit_cast(float, u);
}

// -------- Fused dequant + GEMM with device-side dtype detection --------
// out[m,n] = sum_k x[m,k]*W[n,k] + bias[n]
// 128x128 tile, BK=32, 256 threads = 4 waves (2x2), each wave 4x4 MFMA 16x16x32 bf16.
// The harness's dtype conversion for fp16 inputs (and possibly f32) is ambiguous
// (round-1/2 absmax 43012 == garbage-value signature, finite, deterministic), so
// thread 0 classifies each float tensor's actual storage from its leading bytes:
//   x, bias: f32 vs bf16 — for true f32, the LOW halfword of each float is random
//     mantissa bits (P(sane bf16 exponent) ~ 0.28/elt); for bf16 storage every
//     halfword is a sane small value. 64 probes -> misclassify P ~ 1e-35.
//   norm in [0.01,1]: fp16 vs bf16 vs f32 — bf16 values read as fp16 land in
//     [1,2); fp16 values read as bf16 land <= 0.0078; f32 halves are random.
//     Strict range (0.0085, 1.02) separates all three.
__global__ __launch_bounds__(256, 2) void gemm_fused(
        const void* __restrict__ xv,
        const int* __restrict__ q4, const void* __restrict__ nrmv,
        const void* __restrict__ biasv, float* __restrict__ out) {
    __shared__ __align__(16) __bf16 As[128 * 32];
    __shared__ __align__(16) __bf16 Bs[128 * 32];
    __shared__ int s_modes[3];

    const int tid = threadIdx.x;

    if (tid == 0) {
        // ---- x: 1 = bf16 storage, 0 = f32 storage ----
        int xm = 1;
        const unsigned short* px = (const unsigned short*)xv;
        for (int i = 0; i < 128; i += 2) {          // even halfwords, 254 B < any x size
            unsigned short h = px[i];
            int e = (h >> 7) & 0xFF;
            if (!((e >= 64 && e <= 134) || (h & 0x7FFF) == 0)) { xm = 0; break; }
        }
        // ---- norm: 0 = fp16, 1 = bf16, 2 = f32 ----
        const unsigned short* pn = (const unsigned short*)nrmv;
        bool ok16 = true, okbf = true;
        for (int i = 0; i < 32; ++i) {              // 64 B < 2 MB min size
            unsigned short h = pn[i];
            float v16 = __half2float(__builtin_bit_cast(__half, h));
            float vbf = bfbits(h);
            if (!(v16 > 0.0085f && v16 < 1.02f)) ok16 = false;  // NaN -> false ✓
            if (!(vbf > 0.0085f && vbf < 1.02f)) okbf = false;
        }
        // ---- bias: 1 = bf16, 0 = f32 ----
        int bm = 1;
        const unsigned short* pb = (const unsigned short*)biasv;
        for (int i = 0; i < 128; i += 2) {          // 254 B < 8 KB min size
            unsigned short h = pb[i];
            int e = (h >> 7) & 0xFF;
            if (!((e >= 64 && e <= 134) || (h & 0x7FFF) == 0)) { bm = 0; break; }
        }
        s_modes[0] = xm;
        s_modes[1] = ok16 ? 0 : (okbf ? 1 : 2);
        s_modes[2] = bm;
    }
    __syncthreads();
    const int xmode = s_modes[0];
    const int nmode = s_modes[1];
    const int bmode = s_modes[2];

    const int bid = blockIdx.x;
    const int n0 = (bid & 31) * 128;   // n fastest: concurrent blocks share x rows
    const int m0 = (bid >> 5) * 128;

    const int w  = tid >> 6;   // wave id 0..3
    const int l  = tid & 63;   // lane
    const int r  = l & 15;
    const int q  = l >> 4;
    const int wm = (w >> 1) * 64;
    const int wn = (w & 1) * 64;

    // A staging: thread covers 16 elements of the 128x32 tile
    const int arow = tid >> 1;
    const int acol = (tid & 1) * 16;
    const size_t aoff = (size_t)(m0 + arow) * K_IN + acol;

    // B staging: thread dequantizes one 16-wide group (row = tid/2, half = tid&1)
    const int brow = tid >> 1;
    const int bgc  = tid & 1;

    // bias folded into accumulator init: C/D col = lane&15 = r
    f32x4 acc[4][4];
#pragma unroll
    for (int j = 0; j < 4; ++j) {
        const int bidx = n0 + wn + j * 16 + r;
        float bv = (bmode == 0) ? ((const float*)biasv)[bidx]
                                : bfbits(((const unsigned short*)biasv)[bidx]);
#pragma unroll
        for (int i = 0; i < 4; ++i) {
            acc[i][j][0] = bv; acc[i][j][1] = bv; acc[i][j][2] = bv; acc[i][j][3] = bv;
        }
    }

    for (int k0 = 0; k0 < K_IN; k0 += 32) {
        __syncthreads();   // previous iteration's LDS reads complete

        // ---- B tile: inline dequant of group (n0+brow, k in [k0+bgc*16, +16)) ----
        {
            const int g = (n0 + brow) * (K_IN / GRP) + (k0 >> 4) + bgc;
            const int4* qp = (const int4*)q4 + (size_t)g * 2;   // 8 int32 = 16 nibble pairs
            int4 a4 = qp[0], c4 = qp[1];
            float nm;
            if (nmode == 0)      nm = __half2float(((const __half*)nrmv)[g]);
            else if (nmode == 1) nm = bfbits(((const unsigned short*)nrmv)[g]);
            else                 nm = ((const float*)nrmv)[g];
            float s = nm * (2.0f / 15.0f);   // w = q*(2*norm/15) - norm
            int qs[8] = {a4.x, a4.y, a4.z, a4.w, c4.x, c4.y, c4.z, c4.w};
            bf16x8 v0, v1;
#pragma unroll
            for (int u = 0; u < 8; ++u) {
                float lo = fmaf((float)(qs[u] & 15), s, -nm);
                float hi = fmaf((float)((qs[u] >> 4) & 15), s, -nm);
                if (u < 4) { v0[2 * u] = (__bf16)lo; v0[2 * u + 1] = (__bf16)hi; }
                else       { v1[2 * (u - 4)] = (__bf16)lo; v1[2 * (u - 4) + 1] = (__bf16)hi; }
            }
            bf16x8* bp = (bf16x8*)(Bs + brow * 32 + bgc * 16);
            bp[0] = v0; bp[1] = v1;
        }

        // ---- A tile: 16 elements per thread, storage-dtype dependent ----
        if (xmode == 0) {
            const float4* ap = (const float4*)((const float*)xv + aoff + k0);
            float4 f0 = ap[0], f1 = ap[1], f2 = ap[2], f3 = ap[3];
            bf16x8 u0, u1;
            u0[0] = (__bf16)f0.x; u0[1] = (__bf16)f0.y; u0[2] = (__bf16)f0.z; u0[3] = (__bf16)f0.w;
            u0[4] = (__bf16)f1.x; u0[5] = (__bf16)f1.y; u0[6] = (__bf16)f1.z; u0[7] = (__bf16)f1.w;
            u1[0] = (__bf16)f2.x; u1[1] = (__bf16)f2.y; u1[2] = (__bf16)f2.z; u1[3] = (__bf16)f2.w;
            u1[4] = (__bf16)f3.x; u1[5] = (__bf16)f3.y; u1[6] = (__bf16)f3.z; u1[7] = (__bf16)f3.w;
            bf16x8* asp = (bf16x8*)(As + arow * 32 + acol);
            asp[0] = u0; asp[1] = u1;
        } else {
            const ushort8* ap = (const ushort8*)((const unsigned short*)xv + aoff + k0);
            ushort8 u0 = ap[0], u1 = ap[1];
            bf16x8* asp = (bf16x8*)(As + arow * 32 + acol);
            asp[0] = __builtin_bit_cast(bf16x8, u0);
            asp[1] = __builtin_bit_cast(bf16x8, u1);
        }

        __syncthreads();   // staging visible to all waves

        // ---- fragments: 8 contiguous bf16 along K (ds_read_b128) ----
        bf16x8 af[4], bf[4];
#pragma unroll
        for (int i = 0; i < 4; ++i)
            af[i] = *(const bf16x8*)(As + (wm + i * 16 + r) * 32 + q * 8);
#pragma unroll
        for (int j = 0; j < 4; ++j)
            bf[j] = *(const bf16x8*)(Bs + (wn + j * 16 + r) * 32 + q * 8);

#pragma unroll
        for (int i = 0; i < 4; ++i)
#pragma unroll
            for (int j = 0; j < 4; ++j)
                acc[i][j] = __builtin_amdgcn_mfma_f32_16x16x32_bf16(
                    af[i], bf[j], acc[i][j], 0, 0, 0);
    }

    // epilogue: C/D map col=lane&15, row=(lane>>4)*4+reg  (m89-verified)
#pragma unroll
    for (int i = 0; i < 4; ++i) {
        const int row = m0 + wm + i * 16 + q * 4;
#pragma unroll
        for (int j = 0; j < 4; ++j) {
            const int col = n0 + wn + j * 16 + r;
            float* p = out + (size_t)row * N_OUT + col;
            p[0 * N_OUT] = acc[i][j][0];
            p[1 * N_OUT] = acc[i][j][1];
            p[2 * N_OUT] = acc[i][j][2];
            p[3 * N_OUT] = acc[i][j][3];
        }
    }
}

extern "C" void kernel_launch(void* const* d_in, const int* in_sizes, int n_in,
                              void* d_out, int out_size, void* d_ws, size_t ws_size,
                              hipStream_t stream) {
    const void* x    = d_in[0];
    const int*  q4   = (const int*)d_in[1];
    const void* nrm  = d_in[2];
    const void* bias = d_in[3];
    float*      out  = (float*)d_out;

    const int gemm_blocks = (M_TOK / 128) * (N_OUT / 128);   // 64*32 = 2048
    gemm_fused<<<gemm_blocks, 256, 0, stream>>>(x, q4, nrm, bias, out);
}